// Round 5
// baseline (9073.413 us; speedup 1.0000x reference)
//
#include <hip/hip_runtime.h>
#include <hip/hip_bf16.h>
#include <hip/hip_cooperative_groups.h>
#include <math.h>

namespace cg = cooperative_groups;

// B=32, T=128, D_IN=32, H1=1024, H=2048, PEN=1024, C=64, P=4
// Inputs/outputs FLOAT32 (+int32 labels). Internals bf16 (threshold 1.02e-2).

typedef __bf16 bf16_t;
typedef __bf16 bf16x8 __attribute__((ext_vector_type(8)));
typedef float  f32x4  __attribute__((ext_vector_type(4)));

static __device__ __forceinline__ void zero4(f32x4& v) {
  v[0] = 0.0f; v[1] = 0.0f; v[2] = 0.0f; v[3] = 0.0f;
}

template <typename T>
static __device__ __forceinline__ bf16x8 load8_as_bf16(const T* p);
template <>
__device__ __forceinline__ bf16x8 load8_as_bf16<bf16_t>(const bf16_t* p) {
  return *(const bf16x8*)p;
}
template <>
__device__ __forceinline__ bf16x8 load8_as_bf16<float>(const float* p) {
  bf16x8 v;
#pragma unroll
  for (int u = 0; u < 8; ++u) v[u] = (bf16_t)p[u];
  return v;
}

// ---------------------------------------------------------------------------
// GEMM: C[M,N] = act(A[M,K] * Bm[N,K]^T + bias[N]), row-major, bf16 C.
// 128x128 tile, BK=32, 4 waves 2x2, mfma_f32_16x16x32_bf16. (round-4, passing)
// ---------------------------------------------------------------------------
template <typename TA, typename TB>
__global__ __launch_bounds__(256) void gemm_bt(
    const TA* __restrict__ A, const TB* __restrict__ Bm,
    const float* __restrict__ bias, bf16_t* __restrict__ C,
    int M, int N, int K, int relu)
{
  __shared__ __align__(16) bf16_t As[128 * 32];
  __shared__ __align__(16) bf16_t Bs[128 * 32];

  const int tid  = threadIdx.x;
  const int lane = tid & 63;
  const int wave = tid >> 6;
  const int q    = lane >> 4;
  const int l15  = lane & 15;
  const int wr   = wave >> 1;
  const int wc   = wave & 1;
  const int m0   = blockIdx.y * 128;
  const int n0   = blockIdx.x * 128;

  f32x4 acc[4][4];
#pragma unroll
  for (int i = 0; i < 4; ++i)
#pragma unroll
    for (int j = 0; j < 4; ++j) zero4(acc[i][j]);

  const int se = wave * 512 + lane * 8;

  const int kt_count = K >> 5;
  for (int kt = 0; kt < kt_count; ++kt) {
    const int k0 = kt << 5;

    bf16x8 av[2], bv[2];
#pragma unroll
    for (int c = 0; c < 2; ++c) {
      const int e   = c * 2048 + se;
      const int row = e >> 5;
      const int col = e & 31;
      av[c] = load8_as_bf16<TA>(&A [(size_t)(m0 + row) * K + k0 + col]);
      bv[c] = load8_as_bf16<TB>(&Bm[(size_t)(n0 + row) * K + k0 + col]);
    }

    __syncthreads();
#pragma unroll
    for (int c = 0; c < 2; ++c) {
      *(bf16x8*)&As[c * 2048 + se] = av[c];
      *(bf16x8*)&Bs[c * 2048 + se] = bv[c];
    }
    __syncthreads();

    bf16x8 af[4], bfv[4];
#pragma unroll
    for (int i = 0; i < 4; ++i)
      af[i] = *(const bf16x8*)&As[(wr * 64 + i * 16 + l15) * 32 + q * 8];
#pragma unroll
    for (int j = 0; j < 4; ++j)
      bfv[j] = *(const bf16x8*)&Bs[(wc * 64 + j * 16 + l15) * 32 + q * 8];

#pragma unroll
    for (int i = 0; i < 4; ++i)
#pragma unroll
      for (int j = 0; j < 4; ++j)
        acc[i][j] = __builtin_amdgcn_mfma_f32_16x16x32_bf16(af[i], bfv[j], acc[i][j], 0, 0, 0);
  }

#pragma unroll
  for (int j = 0; j < 4; ++j) {
    const int n = n0 + wc * 64 + j * 16 + l15;
    const float bvl = bias[n];
#pragma unroll
    for (int i = 0; i < 4; ++i) {
      const int mbase = m0 + wr * 64 + i * 16 + q * 4;
#pragma unroll
      for (int r = 0; r < 4; ++r) {
        float v = acc[i][j][r] + bvl;
        if (relu) v = v > 0.0f ? v : 0.0f;
        C[(size_t)(mbase + r) * N + n] = (bf16_t)v;
      }
    }
  }
}

// ---------------------------------------------------------------------------
__global__ __launch_bounds__(256) void cvt_f32_bf16(
    const float* __restrict__ s, bf16_t* __restrict__ d, int n8)
{
  const int i = blockIdx.x * 256 + threadIdx.x;
  if (i < n8) {
    const float* p = s + (size_t)i * 8;
    bf16x8 v;
#pragma unroll
    for (int u = 0; u < 8; ++u) v[u] = (bf16_t)p[u];
    *(bf16x8*)(d + (size_t)i * 8) = v;
  }
}

// ---------------------------------------------------------------------------
// Persistent cooperative GRU: 256 WGs x 256 threads, all 128 time steps in
// one dispatch, grid.sync() between steps. Matmul/pointwise body identical
// to the round-4 per-step kernel (passing). WG owns 8 h-columns j0..j0+7.
// ---------------------------------------------------------------------------
__global__ __launch_bounds__(256) void gru_persistent(
    const bf16_t* __restrict__ W_hhb, const float* __restrict__ b_hh,
    const bf16_t* __restrict__ xp,    bf16_t* __restrict__ hs)
{
  cg::grid_group grid = cg::this_grid();

  __shared__ __align__(16) float hp_s[32][33];

  const int tid  = threadIdx.x;
  const int lane = tid & 63;
  const int wave = tid >> 6;
  const int q    = lane >> 4;
  const int l15  = lane & 15;
  const int mt   = wave >> 1;   // m-tile (gate rows)
  const int nt   = wave & 1;    // n-tile (batch)
  const int j0   = blockIdx.x * 8;

  const int m_local = mt * 16 + l15;
  int gate = m_local >> 3; if (gate > 2) gate = 2;   // rows 24..31 unused
  const bf16_t* arow = W_hhb + ((size_t)gate * 2048 + j0 + (m_local & 7)) * 2048;
  const int bcol = nt * 16 + l15;

  // pointwise indices
  const int pb  = tid >> 3;
  const int pjj = tid & 7;
  const int pjg = j0 + pjj;
  const float bh_r = b_hh[pjg];
  const float bh_z = b_hh[2048 + pjg];
  const float bh_n = b_hh[4096 + pjg];

  for (int t = 0; t < 128; ++t) {
    f32x4 acc; zero4(acc);
    if (t > 0) {
      const bf16_t* brow = hs + ((size_t)bcol * 128 + (t - 1)) * 2048;
      f32x4 acc0, acc1; zero4(acc0); zero4(acc1);
      for (int k = 0; k < 2048; k += 64) {
        bf16x8 a0 = *(const bf16x8*)&arow[k + q * 8];
        bf16x8 b0 = *(const bf16x8*)&brow[k + q * 8];
        bf16x8 a1 = *(const bf16x8*)&arow[k + 32 + q * 8];
        bf16x8 b1 = *(const bf16x8*)&brow[k + 32 + q * 8];
        acc0 = __builtin_amdgcn_mfma_f32_16x16x32_bf16(a0, b0, acc0, 0, 0, 0);
        acc1 = __builtin_amdgcn_mfma_f32_16x16x32_bf16(a1, b1, acc1, 0, 0, 0);
      }
      acc = acc0 + acc1;
    }

#pragma unroll
    for (int r = 0; r < 4; ++r) {
      const int ml = mt * 16 + q * 4 + r;
      if (ml < 24) hp_s[ml][nt * 16 + l15] = acc[r];
    }
    __syncthreads();

    const size_t xrow = (size_t)(pb * 128 + t) * 6144;
    const float xr = (float)xp[xrow + pjg];
    const float xz = (float)xp[xrow + 2048 + pjg];
    const float xn = (float)xp[xrow + 4096 + pjg];
    const float hr = hp_s[pjj][pb]      + bh_r;
    const float hz = hp_s[8 + pjj][pb]  + bh_z;
    const float hn = hp_s[16 + pjj][pb] + bh_n;
    const float r_ = 1.0f / (1.0f + __expf(-(xr + hr)));
    const float z_ = 1.0f / (1.0f + __expf(-(xz + hz)));
    const float n_ = tanhf(xn + r_ * hn);
    const float hp = (t > 0) ? (float)hs[((size_t)pb * 128 + (t - 1)) * 2048 + pjg] : 0.0f;
    const float hnew = (1.0f - z_) * n_ + z_ * hp;
    hs[((size_t)pb * 128 + t) * 2048 + pjg] = (bf16_t)hnew;

    __threadfence();   // make h_t visible device-wide before the barrier
    grid.sync();       // all WGs advance to step t+1 together
  }
}

// ---------------------------------------------------------------------------
// Heads: per (b,t): 3 scalar + 4 sigmoid heads, 1024-dot each, f32 out.
// ---------------------------------------------------------------------------
__global__ __launch_bounds__(256) void heads_kernel(
    const bf16_t* __restrict__ out_s, const int* __restrict__ labels,
    const float* __restrict__ W4, const float* __restrict__ b4,
    const float* __restrict__ W5, const float* __restrict__ b5,
    const float* __restrict__ W6, const float* __restrict__ b6,
    const float* __restrict__ Wp, const float* __restrict__ bp,
    float* __restrict__ out)
{
  const int bt  = blockIdx.x;
  const int b   = bt >> 7;         // T = 128
  const int lab = labels[b];
  const bf16_t* os  = out_s + (size_t)bt * 1024;
  const float* w4  = W4 + (size_t)lab * 1024;
  const float* w5  = W5 + (size_t)lab * 1024;
  const float* w6  = W6 + (size_t)lab * 1024;
  const float* wp0 = Wp + (size_t)lab * 1024;

  float s[7] = {0, 0, 0, 0, 0, 0, 0};
  for (int d = threadIdx.x; d < 1024; d += 256) {
    const float v = (float)os[d];
    s[0] += v * w4[d];
    s[1] += v * w5[d];
    s[2] += v * w6[d];
    s[3] += v * wp0[d];
    s[4] += v * wp0[65536 + d];
    s[5] += v * wp0[131072 + d];
    s[6] += v * wp0[196608 + d];
  }
#pragma unroll
  for (int i = 0; i < 7; ++i)
    for (int off = 32; off > 0; off >>= 1)
      s[i] += __shfl_down(s[i], off, 64);

  __shared__ float red[4][7];
  const int lane = threadIdx.x & 63, wave = threadIdx.x >> 6;
  if (lane == 0)
    for (int i = 0; i < 7; ++i) red[wave][i] = s[i];
  __syncthreads();
  if (threadIdx.x == 0) {
    float tsum[7];
    for (int i = 0; i < 7; ++i)
      tsum[i] = red[0][i] + red[1][i] + red[2][i] + red[3][i];
    out[bt]        = tsum[0] + b4[lab];
    out[4096 + bt] = tsum[1] + b5[lab];
    out[8192 + bt] = tsum[2] + b6[lab];
#pragma unroll
    for (int p = 0; p < 4; ++p) {
      const float v = tsum[3 + p] + bp[p * 64 + lab];
      out[12288 + p * 4096 + bt] = 1.0f / (1.0f + __expf(-v));
    }
  }
}

// ---------------------------------------------------------------------------
extern "C" void kernel_launch(void* const* d_in, const int* in_sizes, int n_in,
                              void* d_out, int out_size, void* d_ws, size_t ws_size,
                              hipStream_t stream)
{
  const float* x     = (const float*)d_in[0];
  const int*   label = (const int*)d_in[1];
  const float* W1    = (const float*)d_in[2];
  const float* b1    = (const float*)d_in[3];
  const float* W2    = (const float*)d_in[4];
  const float* b2    = (const float*)d_in[5];
  const float* W_ih  = (const float*)d_in[6];
  const float* b_ih  = (const float*)d_in[7];
  const float* W_hh  = (const float*)d_in[8];
  const float* b_hh  = (const float*)d_in[9];
  const float* W3    = (const float*)d_in[10];
  const float* b3    = (const float*)d_in[11];
  const float* W4    = (const float*)d_in[12];
  const float* b4    = (const float*)d_in[13];
  const float* W5    = (const float*)d_in[14];
  const float* b5    = (const float*)d_in[15];
  const float* W6    = (const float*)d_in[16];
  const float* b6    = (const float*)d_in[17];
  const float* Wp    = (const float*)d_in[18];
  const float* bp    = (const float*)d_in[19];

  // Workspace (96 MB peak):
  //   W_hhb [0,24MB)   bf16 copy of W_hh (persistent)
  //   out1  [24,32MB)  4096x1024  — dead after layer2
  //   out2  [32,48MB)  4096x2048  — dead after xp GEMM
  //   xp    [48,96MB)  4096x6144  — live through GRU
  //   hs    [24,40MB)  (B,T,2048) — overlays out1+out2-head (dead)
  //   out_s [40,48MB)  4096x1024  — overlays out2 tail (dead)
  char* ws = (char*)d_ws;
  bf16_t* W_hhb = (bf16_t*)(ws);
  bf16_t* out1  = (bf16_t*)(ws + (24u << 20));
  bf16_t* out2  = (bf16_t*)(ws + (32u << 20));
  bf16_t* xp    = (bf16_t*)(ws + (48u << 20));
  bf16_t* hs    = (bf16_t*)(ws + (24u << 20));
  bf16_t* out_s = (bf16_t*)(ws + (40u << 20));
  float*  outp  = (float*)d_out;

  hipMemsetAsync(d_out, 0, (size_t)out_size * sizeof(float), stream);

  dim3 blk(256);
  // W_hh f32 -> bf16
  cvt_f32_bf16<<<dim3(6144), blk, 0, stream>>>(W_hh, W_hhb, 1572864);
  // layer1: (4096x32)*(1024x32)^T, relu
  gemm_bt<float, float><<<dim3(8, 32), blk, 0, stream>>>(x, W1, b1, out1, 4096, 1024, 32, 1);
  // layer2: (4096x1024)*(2048x1024)^T, relu
  gemm_bt<bf16_t, float><<<dim3(16, 32), blk, 0, stream>>>(out1, W2, b2, out2, 4096, 2048, 1024, 1);
  // xp: (4096x2048)*(6144x2048)^T + b_ih
  gemm_bt<bf16_t, float><<<dim3(48, 32), blk, 0, stream>>>(out2, W_ih, b_ih, xp, 4096, 6144, 2048, 0);
  // GRU: one persistent cooperative dispatch, 128 steps with grid.sync()
  {
    void* args[] = {(void*)&W_hhb, (void*)&b_hh, (void*)&xp, (void*)&hs};
    hipLaunchCooperativeKernel((const void*)gru_persistent,
                               dim3(256), blk, args, 0, stream);
  }
  // layer3: (4096x2048)*(1024x2048)^T, relu
  gemm_bt<bf16_t, float><<<dim3(8, 32), blk, 0, stream>>>(hs, W3, b3, out_s, 4096, 1024, 2048, 1);
  // heads (f32 weights, f32 out)
  heads_kernel<<<dim3(4096), blk, 0, stream>>>(out_s, label, W4, b4, W5, b5, W6, b6, Wp, bp, outp);
}

// Round 6
// 3996.067 us; speedup vs baseline: 2.2706x; 2.2706x over previous
//
#include <hip/hip_runtime.h>
#include <hip/hip_bf16.h>
#include <math.h>

// B=32, T=128, D_IN=32, H1=1024, H=2048, PEN=1024, C=64, P=4
// Inputs/outputs FLOAT32 (+int32 labels). Internals bf16 (threshold 1.02e-2).

typedef __bf16 bf16_t;
typedef __bf16 bf16x8 __attribute__((ext_vector_type(8)));
typedef float  f32x4  __attribute__((ext_vector_type(4)));

static __device__ __forceinline__ void zero4(f32x4& v) {
  v[0] = 0.0f; v[1] = 0.0f; v[2] = 0.0f; v[3] = 0.0f;
}

template <typename T>
static __device__ __forceinline__ bf16x8 load8_as_bf16(const T* p);
template <>
__device__ __forceinline__ bf16x8 load8_as_bf16<bf16_t>(const bf16_t* p) {
  return *(const bf16x8*)p;
}
template <>
__device__ __forceinline__ bf16x8 load8_as_bf16<float>(const float* p) {
  bf16x8 v;
#pragma unroll
  for (int u = 0; u < 8; ++u) v[u] = (bf16_t)p[u];
  return v;
}

// ---------------------------------------------------------------------------
// GEMM: C[M,N] = act(A[M,K] * Bm[N,K]^T + bias[N]), row-major, bf16 C.
// 128x128 tile, BK=32, 4 waves 2x2, mfma_f32_16x16x32_bf16. (round-4, passing)
// ---------------------------------------------------------------------------
template <typename TA, typename TB>
__global__ __launch_bounds__(256) void gemm_bt(
    const TA* __restrict__ A, const TB* __restrict__ Bm,
    const float* __restrict__ bias, bf16_t* __restrict__ C,
    int M, int N, int K, int relu)
{
  __shared__ __align__(16) bf16_t As[128 * 32];
  __shared__ __align__(16) bf16_t Bs[128 * 32];

  const int tid  = threadIdx.x;
  const int lane = tid & 63;
  const int wave = tid >> 6;
  const int q    = lane >> 4;
  const int l15  = lane & 15;
  const int wr   = wave >> 1;
  const int wc   = wave & 1;
  const int m0   = blockIdx.y * 128;
  const int n0   = blockIdx.x * 128;

  f32x4 acc[4][4];
#pragma unroll
  for (int i = 0; i < 4; ++i)
#pragma unroll
    for (int j = 0; j < 4; ++j) zero4(acc[i][j]);

  const int se = wave * 512 + lane * 8;

  const int kt_count = K >> 5;
  for (int kt = 0; kt < kt_count; ++kt) {
    const int k0 = kt << 5;

    bf16x8 av[2], bv[2];
#pragma unroll
    for (int c = 0; c < 2; ++c) {
      const int e   = c * 2048 + se;
      const int row = e >> 5;
      const int col = e & 31;
      av[c] = load8_as_bf16<TA>(&A [(size_t)(m0 + row) * K + k0 + col]);
      bv[c] = load8_as_bf16<TB>(&Bm[(size_t)(n0 + row) * K + k0 + col]);
    }

    __syncthreads();
#pragma unroll
    for (int c = 0; c < 2; ++c) {
      *(bf16x8*)&As[c * 2048 + se] = av[c];
      *(bf16x8*)&Bs[c * 2048 + se] = bv[c];
    }
    __syncthreads();

    bf16x8 af[4], bfv[4];
#pragma unroll
    for (int i = 0; i < 4; ++i)
      af[i] = *(const bf16x8*)&As[(wr * 64 + i * 16 + l15) * 32 + q * 8];
#pragma unroll
    for (int j = 0; j < 4; ++j)
      bfv[j] = *(const bf16x8*)&Bs[(wc * 64 + j * 16 + l15) * 32 + q * 8];

#pragma unroll
    for (int i = 0; i < 4; ++i)
#pragma unroll
      for (int j = 0; j < 4; ++j)
        acc[i][j] = __builtin_amdgcn_mfma_f32_16x16x32_bf16(af[i], bfv[j], acc[i][j], 0, 0, 0);
  }

#pragma unroll
  for (int j = 0; j < 4; ++j) {
    const int n = n0 + wc * 64 + j * 16 + l15;
    const float bvl = bias[n];
#pragma unroll
    for (int i = 0; i < 4; ++i) {
      const int mbase = m0 + wr * 64 + i * 16 + q * 4;
#pragma unroll
      for (int r = 0; r < 4; ++r) {
        float v = acc[i][j][r] + bvl;
        if (relu) v = v > 0.0f ? v : 0.0f;
        C[(size_t)(mbase + r) * N + n] = (bf16_t)v;
      }
    }
  }
}

// ---------------------------------------------------------------------------
__global__ __launch_bounds__(256) void cvt_f32_bf16(
    const float* __restrict__ s, bf16_t* __restrict__ d, int n8)
{
  const int i = blockIdx.x * 256 + threadIdx.x;
  if (i < n8) {
    const float* p = s + (size_t)i * 8;
    bf16x8 v;
#pragma unroll
    for (int u = 0; u < 8; ++u) v[u] = (bf16_t)p[u];
    *(bf16x8*)(d + (size_t)i * 8) = v;
  }
}

// ---------------------------------------------------------------------------
// Persistent GRU with HAND-ROLLED grid barrier (cg::grid.sync measured at
// ~65 us/step — replaced). bar[0] = monotone release flag; bar[1+t] = step-t
// arrival counter. 256 WGs x 256 threads; WG owns 8 h-columns j0..j0+7.
// Matmul/pointwise body identical to round-4 passing code.
// ---------------------------------------------------------------------------
__global__ __launch_bounds__(256) void gru_persistent(
    const bf16_t* __restrict__ W_hhb, const float* __restrict__ b_hh,
    const bf16_t* __restrict__ xp,    bf16_t* __restrict__ hs,
    unsigned* bar)
{
  __shared__ __align__(16) float hp_s[32][33];

  const int tid  = threadIdx.x;
  const int lane = tid & 63;
  const int wave = tid >> 6;
  const int q    = lane >> 4;
  const int l15  = lane & 15;
  const int mt   = wave >> 1;   // m-tile (gate rows)
  const int nt   = wave & 1;    // n-tile (batch)
  const int j0   = blockIdx.x * 8;

  const int m_local = mt * 16 + l15;
  int gate = m_local >> 3; if (gate > 2) gate = 2;   // rows 24..31 unused
  const bf16_t* arow = W_hhb + ((size_t)gate * 2048 + j0 + (m_local & 7)) * 2048;
  const int bcol = nt * 16 + l15;

  // pointwise indices
  const int pb  = tid >> 3;
  const int pjj = tid & 7;
  const int pjg = j0 + pjj;
  const float bh_r = b_hh[pjg];
  const float bh_z = b_hh[2048 + pjg];
  const float bh_n = b_hh[4096 + pjg];

  for (int t = 0; t < 128; ++t) {
    f32x4 acc; zero4(acc);
    if (t > 0) {
      const bf16_t* brow = hs + ((size_t)bcol * 128 + (t - 1)) * 2048;
      f32x4 acc0, acc1; zero4(acc0); zero4(acc1);
      for (int k = 0; k < 2048; k += 64) {
        bf16x8 a0 = *(const bf16x8*)&arow[k + q * 8];
        bf16x8 b0 = *(const bf16x8*)&brow[k + q * 8];
        bf16x8 a1 = *(const bf16x8*)&arow[k + 32 + q * 8];
        bf16x8 b1 = *(const bf16x8*)&brow[k + 32 + q * 8];
        acc0 = __builtin_amdgcn_mfma_f32_16x16x32_bf16(a0, b0, acc0, 0, 0, 0);
        acc1 = __builtin_amdgcn_mfma_f32_16x16x32_bf16(a1, b1, acc1, 0, 0, 0);
      }
      acc = acc0 + acc1;
    }

#pragma unroll
    for (int r = 0; r < 4; ++r) {
      const int ml = mt * 16 + q * 4 + r;
      if (ml < 24) hp_s[ml][nt * 16 + l15] = acc[r];
    }
    __syncthreads();

    const size_t xrow = (size_t)(pb * 128 + t) * 6144;
    const float xr = (float)xp[xrow + pjg];
    const float xz = (float)xp[xrow + 2048 + pjg];
    const float xn = (float)xp[xrow + 4096 + pjg];
    const float hr = hp_s[pjj][pb]      + bh_r;
    const float hz = hp_s[8 + pjj][pb]  + bh_z;
    const float hn = hp_s[16 + pjj][pb] + bh_n;
    const float r_ = 1.0f / (1.0f + __expf(-(xr + hr)));
    const float z_ = 1.0f / (1.0f + __expf(-(xz + hz)));
    const float n_ = tanhf(xn + r_ * hn);
    const float hp = (t > 0) ? (float)hs[((size_t)pb * 128 + (t - 1)) * 2048 + pjg] : 0.0f;
    const float hnew = (1.0f - z_) * n_ + z_ * hp;
    hs[((size_t)pb * 128 + t) * 2048 + pjg] = (bf16_t)hnew;

    if (t < 127) {
      __syncthreads();               // all waves: step-t work (incl. hs write) issued
      if (tid == 0) {
        __threadfence();             // release: hs stores visible device-wide
        unsigned arr = __hip_atomic_fetch_add(&bar[1 + t], 1u,
                          __ATOMIC_RELAXED, __HIP_MEMORY_SCOPE_AGENT);
        if (arr == 255u) {
          __hip_atomic_store(&bar[0], (unsigned)(t + 1),
                             __ATOMIC_RELEASE, __HIP_MEMORY_SCOPE_AGENT);
        } else {
          while (__hip_atomic_load(&bar[0],
                    __ATOMIC_RELAXED, __HIP_MEMORY_SCOPE_AGENT) < (unsigned)(t + 1))
            __builtin_amdgcn_s_sleep(2);
        }
        __threadfence();             // acquire: drop stale L1/L2 lines
      }
      __syncthreads();               // whole WG proceeds to step t+1
    }
  }
}

// ---------------------------------------------------------------------------
// Heads: per (b,t): 3 scalar + 4 sigmoid heads, 1024-dot each, f32 out.
// ---------------------------------------------------------------------------
__global__ __launch_bounds__(256) void heads_kernel(
    const bf16_t* __restrict__ out_s, const int* __restrict__ labels,
    const float* __restrict__ W4, const float* __restrict__ b4,
    const float* __restrict__ W5, const float* __restrict__ b5,
    const float* __restrict__ W6, const float* __restrict__ b6,
    const float* __restrict__ Wp, const float* __restrict__ bp,
    float* __restrict__ out)
{
  const int bt  = blockIdx.x;
  const int b   = bt >> 7;         // T = 128
  const int lab = labels[b];
  const bf16_t* os  = out_s + (size_t)bt * 1024;
  const float* w4  = W4 + (size_t)lab * 1024;
  const float* w5  = W5 + (size_t)lab * 1024;
  const float* w6  = W6 + (size_t)lab * 1024;
  const float* wp0 = Wp + (size_t)lab * 1024;

  float s[7] = {0, 0, 0, 0, 0, 0, 0};
  for (int d = threadIdx.x; d < 1024; d += 256) {
    const float v = (float)os[d];
    s[0] += v * w4[d];
    s[1] += v * w5[d];
    s[2] += v * w6[d];
    s[3] += v * wp0[d];
    s[4] += v * wp0[65536 + d];
    s[5] += v * wp0[131072 + d];
    s[6] += v * wp0[196608 + d];
  }
#pragma unroll
  for (int i = 0; i < 7; ++i)
    for (int off = 32; off > 0; off >>= 1)
      s[i] += __shfl_down(s[i], off, 64);

  __shared__ float red[4][7];
  const int lane = threadIdx.x & 63, wave = threadIdx.x >> 6;
  if (lane == 0)
    for (int i = 0; i < 7; ++i) red[wave][i] = s[i];
  __syncthreads();
  if (threadIdx.x == 0) {
    float tsum[7];
    for (int i = 0; i < 7; ++i)
      tsum[i] = red[0][i] + red[1][i] + red[2][i] + red[3][i];
    out[bt]        = tsum[0] + b4[lab];
    out[4096 + bt] = tsum[1] + b5[lab];
    out[8192 + bt] = tsum[2] + b6[lab];
#pragma unroll
    for (int p = 0; p < 4; ++p) {
      const float v = tsum[3 + p] + bp[p * 64 + lab];
      out[12288 + p * 4096 + bt] = 1.0f / (1.0f + __expf(-v));
    }
  }
}

// ---------------------------------------------------------------------------
extern "C" void kernel_launch(void* const* d_in, const int* in_sizes, int n_in,
                              void* d_out, int out_size, void* d_ws, size_t ws_size,
                              hipStream_t stream)
{
  const float* x     = (const float*)d_in[0];
  const int*   label = (const int*)d_in[1];
  const float* W1    = (const float*)d_in[2];
  const float* b1    = (const float*)d_in[3];
  const float* W2    = (const float*)d_in[4];
  const float* b2    = (const float*)d_in[5];
  const float* W_ih  = (const float*)d_in[6];
  const float* b_ih  = (const float*)d_in[7];
  const float* W_hh  = (const float*)d_in[8];
  const float* b_hh  = (const float*)d_in[9];
  const float* W3    = (const float*)d_in[10];
  const float* b3    = (const float*)d_in[11];
  const float* W4    = (const float*)d_in[12];
  const float* b4    = (const float*)d_in[13];
  const float* W5    = (const float*)d_in[14];
  const float* b5    = (const float*)d_in[15];
  const float* W6    = (const float*)d_in[16];
  const float* b6    = (const float*)d_in[17];
  const float* Wp    = (const float*)d_in[18];
  const float* bp    = (const float*)d_in[19];

  // Workspace (96 MB peak):
  //   W_hhb [0,24MB)   bf16 copy of W_hh (persistent)
  //   out1  [24,32MB)  4096x1024  — dead after layer2
  //   out2  [32,48MB)  4096x2048  — dead after xp GEMM
  //   xp    [48,96MB)  4096x6144  — live through GRU
  //   hs    [24,40MB)  (B,T,2048) — overlays out1+out2-head (dead)
  //   bar   [40MB,+1KB) barrier state — overlays out2 tail (dead after xp GEMM),
  //                     memset'd between xp GEMM and the GRU dispatch
  //   out_s [40,48MB)  4096x1024  — overlays out2 tail / bar (both dead)
  char* ws = (char*)d_ws;
  bf16_t*   W_hhb = (bf16_t*)(ws);
  bf16_t*   out1  = (bf16_t*)(ws + (24u << 20));
  bf16_t*   out2  = (bf16_t*)(ws + (32u << 20));
  bf16_t*   xp    = (bf16_t*)(ws + (48u << 20));
  bf16_t*   hs    = (bf16_t*)(ws + (24u << 20));
  unsigned* bar   = (unsigned*)(ws + (40u << 20));
  bf16_t*   out_s = (bf16_t*)(ws + (40u << 20));
  float*    outp  = (float*)d_out;

  hipMemsetAsync(d_out, 0, (size_t)out_size * sizeof(float), stream);

  dim3 blk(256);
  // W_hh f32 -> bf16
  cvt_f32_bf16<<<dim3(6144), blk, 0, stream>>>(W_hh, W_hhb, 1572864);
  // layer1: (4096x32)*(1024x32)^T, relu
  gemm_bt<float, float><<<dim3(8, 32), blk, 0, stream>>>(x, W1, b1, out1, 4096, 1024, 32, 1);
  // layer2: (4096x1024)*(2048x1024)^T, relu
  gemm_bt<bf16_t, float><<<dim3(16, 32), blk, 0, stream>>>(out1, W2, b2, out2, 4096, 2048, 1024, 1);
  // xp: (4096x2048)*(6144x2048)^T + b_ih
  gemm_bt<bf16_t, float><<<dim3(48, 32), blk, 0, stream>>>(out2, W_ih, b_ih, xp, 4096, 6144, 2048, 0);
  // barrier state: zero AFTER xp GEMM consumed out2 (bar overlays out2 tail)
  hipMemsetAsync(bar, 0, 1024, stream);
  // GRU: one persistent dispatch, 128 steps, hand-rolled grid barrier
  {
    void* args[] = {(void*)&W_hhb, (void*)&b_hh, (void*)&xp, (void*)&hs, (void*)&bar};
    hipLaunchCooperativeKernel((const void*)gru_persistent,
                               dim3(256), blk, args, 0, stream);
  }
  // layer3: (4096x2048)*(1024x2048)^T, relu
  gemm_bt<bf16_t, float><<<dim3(8, 32), blk, 0, stream>>>(hs, W3, b3, out_s, 4096, 1024, 2048, 1);
  // heads (f32 weights, f32 out)
  heads_kernel<<<dim3(4096), blk, 0, stream>>>(out_s, label, W4, b4, W5, b5, W6, b6, Wp, bp, outp);
}

// Round 7
// 3801.171 us; speedup vs baseline: 2.3870x; 1.0513x over previous
//
#include <hip/hip_runtime.h>
#include <hip/hip_bf16.h>
#include <math.h>

// B=32, T=128, D_IN=32, H1=1024, H=2048, PEN=1024, C=64, P=4
// Inputs/outputs FLOAT32 (+int32 labels). Internals bf16 (threshold 1.02e-2).

typedef __bf16 bf16_t;
typedef __bf16 bf16x8 __attribute__((ext_vector_type(8)));
typedef float  f32x4  __attribute__((ext_vector_type(4)));

static __device__ __forceinline__ void zero4(f32x4& v) {
  v[0] = 0.0f; v[1] = 0.0f; v[2] = 0.0f; v[3] = 0.0f;
}

template <typename T>
static __device__ __forceinline__ bf16x8 load8_as_bf16(const T* p);
template <>
__device__ __forceinline__ bf16x8 load8_as_bf16<bf16_t>(const bf16_t* p) {
  return *(const bf16x8*)p;
}
template <>
__device__ __forceinline__ bf16x8 load8_as_bf16<float>(const float* p) {
  bf16x8 v;
#pragma unroll
  for (int u = 0; u < 8; ++u) v[u] = (bf16_t)p[u];
  return v;
}

// ---------------------------------------------------------------------------
// GEMM: C[M,N] = act(A[M,K] * Bm[N,K]^T + bias[N]), row-major, bf16 C.
// 128x128 tile, BK=32, 4 waves 2x2, mfma_f32_16x16x32_bf16. (round-4, passing)
// ---------------------------------------------------------------------------
template <typename TA, typename TB>
__global__ __launch_bounds__(256) void gemm_bt(
    const TA* __restrict__ A, const TB* __restrict__ Bm,
    const float* __restrict__ bias, bf16_t* __restrict__ C,
    int M, int N, int K, int relu)
{
  __shared__ __align__(16) bf16_t As[128 * 32];
  __shared__ __align__(16) bf16_t Bs[128 * 32];

  const int tid  = threadIdx.x;
  const int lane = tid & 63;
  const int wave = tid >> 6;
  const int q    = lane >> 4;
  const int l15  = lane & 15;
  const int wr   = wave >> 1;
  const int wc   = wave & 1;
  const int m0   = blockIdx.y * 128;
  const int n0   = blockIdx.x * 128;

  f32x4 acc[4][4];
#pragma unroll
  for (int i = 0; i < 4; ++i)
#pragma unroll
    for (int j = 0; j < 4; ++j) zero4(acc[i][j]);

  const int se = wave * 512 + lane * 8;

  const int kt_count = K >> 5;
  for (int kt = 0; kt < kt_count; ++kt) {
    const int k0 = kt << 5;

    bf16x8 av[2], bv[2];
#pragma unroll
    for (int c = 0; c < 2; ++c) {
      const int e   = c * 2048 + se;
      const int row = e >> 5;
      const int col = e & 31;
      av[c] = load8_as_bf16<TA>(&A [(size_t)(m0 + row) * K + k0 + col]);
      bv[c] = load8_as_bf16<TB>(&Bm[(size_t)(n0 + row) * K + k0 + col]);
    }

    __syncthreads();
#pragma unroll
    for (int c = 0; c < 2; ++c) {
      *(bf16x8*)&As[c * 2048 + se] = av[c];
      *(bf16x8*)&Bs[c * 2048 + se] = bv[c];
    }
    __syncthreads();

    bf16x8 af[4], bfv[4];
#pragma unroll
    for (int i = 0; i < 4; ++i)
      af[i] = *(const bf16x8*)&As[(wr * 64 + i * 16 + l15) * 32 + q * 8];
#pragma unroll
    for (int j = 0; j < 4; ++j)
      bfv[j] = *(const bf16x8*)&Bs[(wc * 64 + j * 16 + l15) * 32 + q * 8];

#pragma unroll
    for (int i = 0; i < 4; ++i)
#pragma unroll
      for (int j = 0; j < 4; ++j)
        acc[i][j] = __builtin_amdgcn_mfma_f32_16x16x32_bf16(af[i], bfv[j], acc[i][j], 0, 0, 0);
  }

#pragma unroll
  for (int j = 0; j < 4; ++j) {
    const int n = n0 + wc * 64 + j * 16 + l15;
    const float bvl = bias[n];
#pragma unroll
    for (int i = 0; i < 4; ++i) {
      const int mbase = m0 + wr * 64 + i * 16 + q * 4;
#pragma unroll
      for (int r = 0; r < 4; ++r) {
        float v = acc[i][j][r] + bvl;
        if (relu) v = v > 0.0f ? v : 0.0f;
        C[(size_t)(mbase + r) * N + n] = (bf16_t)v;
      }
    }
  }
}

// ---------------------------------------------------------------------------
__global__ __launch_bounds__(256) void cvt_f32_bf16(
    const float* __restrict__ s, bf16_t* __restrict__ d, int n8)
{
  const int i = blockIdx.x * 256 + threadIdx.x;
  if (i < n8) {
    const float* p = s + (size_t)i * 8;
    bf16x8 v;
#pragma unroll
    for (int u = 0; u < 8; ++u) v[u] = (bf16_t)p[u];
    *(bf16x8*)(d + (size_t)i * 8) = v;
  }
}

// ---------------------------------------------------------------------------
// Persistent GRU, flag-array grid barrier (v2).
// R6's single arrival counter = 256 serialized cross-XCD RMWs (~25 us/step).
// Now: WG i leader does __threadfence (release/wbl2) then a relaxed store to
// its OWN slot flags[i]; WG0's 256 threads each poll one flag; WG0 leader
// publishes monotone release word bar[0]; spinners poll + __threadfence
// (acquire/inv). bar[0] @ +0, flags @ +128B. All monotone, no reset needed.
// ---------------------------------------------------------------------------
__global__ __launch_bounds__(256) void gru_persistent(
    const bf16_t* __restrict__ W_hhb, const float* __restrict__ b_hh,
    const bf16_t* __restrict__ xp,    bf16_t* __restrict__ hs,
    unsigned* bar)
{
  __shared__ __align__(16) float hp_s[32][33];

  unsigned* flags = bar + 32;   // 256 slots starting at +128B

  const int tid  = threadIdx.x;
  const int lane = tid & 63;
  const int wave = tid >> 6;
  const int q    = lane >> 4;
  const int l15  = lane & 15;
  const int mt   = wave >> 1;   // m-tile (gate rows)
  const int nt   = wave & 1;    // n-tile (batch)
  const int j0   = blockIdx.x * 8;

  const int m_local = mt * 16 + l15;
  int gate = m_local >> 3; if (gate > 2) gate = 2;   // rows 24..31 unused
  const bf16_t* arow = W_hhb + ((size_t)gate * 2048 + j0 + (m_local & 7)) * 2048;
  const int bcol = nt * 16 + l15;

  // pointwise indices
  const int pb  = tid >> 3;
  const int pjj = tid & 7;
  const int pjg = j0 + pjj;
  const float bh_r = b_hh[pjg];
  const float bh_z = b_hh[2048 + pjg];
  const float bh_n = b_hh[4096 + pjg];

  for (int t = 0; t < 128; ++t) {
    f32x4 acc; zero4(acc);
    if (t > 0) {
      const bf16_t* brow = hs + ((size_t)bcol * 128 + (t - 1)) * 2048;
      f32x4 acc0, acc1; zero4(acc0); zero4(acc1);
      for (int k = 0; k < 2048; k += 64) {
        bf16x8 a0 = *(const bf16x8*)&arow[k + q * 8];
        bf16x8 b0 = *(const bf16x8*)&brow[k + q * 8];
        bf16x8 a1 = *(const bf16x8*)&arow[k + 32 + q * 8];
        bf16x8 b1 = *(const bf16x8*)&brow[k + 32 + q * 8];
        acc0 = __builtin_amdgcn_mfma_f32_16x16x32_bf16(a0, b0, acc0, 0, 0, 0);
        acc1 = __builtin_amdgcn_mfma_f32_16x16x32_bf16(a1, b1, acc1, 0, 0, 0);
      }
      acc = acc0 + acc1;
    }

#pragma unroll
    for (int r = 0; r < 4; ++r) {
      const int ml = mt * 16 + q * 4 + r;
      if (ml < 24) hp_s[ml][nt * 16 + l15] = acc[r];
    }
    __syncthreads();

    const size_t xrow = (size_t)(pb * 128 + t) * 6144;
    const float xr = (float)xp[xrow + pjg];
    const float xz = (float)xp[xrow + 2048 + pjg];
    const float xn = (float)xp[xrow + 4096 + pjg];
    const float hr = hp_s[pjj][pb]      + bh_r;
    const float hz = hp_s[8 + pjj][pb]  + bh_z;
    const float hn = hp_s[16 + pjj][pb] + bh_n;
    const float r_ = 1.0f / (1.0f + __expf(-(xr + hr)));
    const float z_ = 1.0f / (1.0f + __expf(-(xz + hz)));
    const float n_ = tanhf(xn + r_ * hn);
    const float hp = (t > 0) ? (float)hs[((size_t)pb * 128 + (t - 1)) * 2048 + pjg] : 0.0f;
    const float hnew = (1.0f - z_) * n_ + z_ * hp;
    hs[((size_t)pb * 128 + t) * 2048 + pjg] = (bf16_t)hnew;

    if (t < 127) {
      const unsigned target = (unsigned)(t + 1);
      __syncthreads();                 // all waves' hs stores drained (vmcnt 0)
      if (tid == 0) {
        __threadfence();               // release: write back this XCD's L2
        __hip_atomic_store(&flags[blockIdx.x], target,
                           __ATOMIC_RELAXED, __HIP_MEMORY_SCOPE_AGENT);
      }
      if (blockIdx.x == 0) {
        // 256 threads <-> 256 flags: one poll round ~ one LLC load latency
        while (__hip_atomic_load(&flags[tid],
                  __ATOMIC_RELAXED, __HIP_MEMORY_SCOPE_AGENT) < target)
          __builtin_amdgcn_s_sleep(1);
        __syncthreads();
        if (tid == 0) {
          __hip_atomic_store(&bar[0], target,
                             __ATOMIC_RELAXED, __HIP_MEMORY_SCOPE_AGENT);
          __threadfence();             // acquire side for WG0's own next step
        }
        __syncthreads();
      } else {
        if (tid == 0) {
          while (__hip_atomic_load(&bar[0],
                    __ATOMIC_RELAXED, __HIP_MEMORY_SCOPE_AGENT) < target)
            __builtin_amdgcn_s_sleep(2);
          __threadfence();             // acquire: invalidate stale L1/L2 lines
        }
        __syncthreads();
      }
    }
  }
}

// ---------------------------------------------------------------------------
// Heads: per (b,t): 3 scalar + 4 sigmoid heads, 1024-dot each, f32 out.
// ---------------------------------------------------------------------------
__global__ __launch_bounds__(256) void heads_kernel(
    const bf16_t* __restrict__ out_s, const int* __restrict__ labels,
    const float* __restrict__ W4, const float* __restrict__ b4,
    const float* __restrict__ W5, const float* __restrict__ b5,
    const float* __restrict__ W6, const float* __restrict__ b6,
    const float* __restrict__ Wp, const float* __restrict__ bp,
    float* __restrict__ out)
{
  const int bt  = blockIdx.x;
  const int b   = bt >> 7;         // T = 128
  const int lab = labels[b];
  const bf16_t* os  = out_s + (size_t)bt * 1024;
  const float* w4  = W4 + (size_t)lab * 1024;
  const float* w5  = W5 + (size_t)lab * 1024;
  const float* w6  = W6 + (size_t)lab * 1024;
  const float* wp0 = Wp + (size_t)lab * 1024;

  float s[7] = {0, 0, 0, 0, 0, 0, 0};
  for (int d = threadIdx.x; d < 1024; d += 256) {
    const float v = (float)os[d];
    s[0] += v * w4[d];
    s[1] += v * w5[d];
    s[2] += v * w6[d];
    s[3] += v * wp0[d];
    s[4] += v * wp0[65536 + d];
    s[5] += v * wp0[131072 + d];
    s[6] += v * wp0[196608 + d];
  }
#pragma unroll
  for (int i = 0; i < 7; ++i)
    for (int off = 32; off > 0; off >>= 1)
      s[i] += __shfl_down(s[i], off, 64);

  __shared__ float red[4][7];
  const int lane = threadIdx.x & 63, wave = threadIdx.x >> 6;
  if (lane == 0)
    for (int i = 0; i < 7; ++i) red[wave][i] = s[i];
  __syncthreads();
  if (threadIdx.x == 0) {
    float tsum[7];
    for (int i = 0; i < 7; ++i)
      tsum[i] = red[0][i] + red[1][i] + red[2][i] + red[3][i];
    out[bt]        = tsum[0] + b4[lab];
    out[4096 + bt] = tsum[1] + b5[lab];
    out[8192 + bt] = tsum[2] + b6[lab];
#pragma unroll
    for (int p = 0; p < 4; ++p) {
      const float v = tsum[3 + p] + bp[p * 64 + lab];
      out[12288 + p * 4096 + bt] = 1.0f / (1.0f + __expf(-v));
    }
  }
}

// ---------------------------------------------------------------------------
extern "C" void kernel_launch(void* const* d_in, const int* in_sizes, int n_in,
                              void* d_out, int out_size, void* d_ws, size_t ws_size,
                              hipStream_t stream)
{
  const float* x     = (const float*)d_in[0];
  const int*   label = (const int*)d_in[1];
  const float* W1    = (const float*)d_in[2];
  const float* b1    = (const float*)d_in[3];
  const float* W2    = (const float*)d_in[4];
  const float* b2    = (const float*)d_in[5];
  const float* W_ih  = (const float*)d_in[6];
  const float* b_ih  = (const float*)d_in[7];
  const float* W_hh  = (const float*)d_in[8];
  const float* b_hh  = (const float*)d_in[9];
  const float* W3    = (const float*)d_in[10];
  const float* b3    = (const float*)d_in[11];
  const float* W4    = (const float*)d_in[12];
  const float* b4    = (const float*)d_in[13];
  const float* W5    = (const float*)d_in[14];
  const float* b5    = (const float*)d_in[15];
  const float* W6    = (const float*)d_in[16];
  const float* b6    = (const float*)d_in[17];
  const float* Wp    = (const float*)d_in[18];
  const float* bp    = (const float*)d_in[19];

  // Workspace (96 MB peak):
  //   W_hhb [0,24MB)   bf16 copy of W_hh (persistent)
  //   out1  [24,32MB)  4096x1024  — dead after layer2
  //   out2  [32,48MB)  4096x2048  — dead after xp GEMM
  //   xp    [48,96MB)  4096x6144  — live through GRU
  //   hs    [24,40MB)  (B,T,2048) — overlays out1+out2-head (dead)
  //   bar   [40MB,+2KB) barrier state — overlays out2 tail (dead after xp GEMM)
  //   out_s [40,48MB)  4096x1024  — overlays bar (dead after GRU)
  char* ws = (char*)d_ws;
  bf16_t*   W_hhb = (bf16_t*)(ws);
  bf16_t*   out1  = (bf16_t*)(ws + (24u << 20));
  bf16_t*   out2  = (bf16_t*)(ws + (32u << 20));
  bf16_t*   xp    = (bf16_t*)(ws + (48u << 20));
  bf16_t*   hs    = (bf16_t*)(ws + (24u << 20));
  unsigned* bar   = (unsigned*)(ws + (40u << 20));
  bf16_t*   out_s = (bf16_t*)(ws + (40u << 20));
  float*    outp  = (float*)d_out;

  hipMemsetAsync(d_out, 0, (size_t)out_size * sizeof(float), stream);

  dim3 blk(256);
  // W_hh f32 -> bf16
  cvt_f32_bf16<<<dim3(6144), blk, 0, stream>>>(W_hh, W_hhb, 1572864);
  // layer1: (4096x32)*(1024x32)^T, relu
  gemm_bt<float, float><<<dim3(8, 32), blk, 0, stream>>>(x, W1, b1, out1, 4096, 1024, 32, 1);
  // layer2: (4096x1024)*(2048x1024)^T, relu
  gemm_bt<bf16_t, float><<<dim3(16, 32), blk, 0, stream>>>(out1, W2, b2, out2, 4096, 2048, 1024, 1);
  // xp: (4096x2048)*(6144x2048)^T + b_ih
  gemm_bt<bf16_t, float><<<dim3(48, 32), blk, 0, stream>>>(out2, W_ih, b_ih, xp, 4096, 6144, 2048, 0);
  // barrier state: zero AFTER xp GEMM consumed out2 (bar overlays out2 tail)
  hipMemsetAsync(bar, 0, 2048, stream);
  // GRU: one persistent dispatch, 128 steps, flag-array grid barrier
  {
    void* args[] = {(void*)&W_hhb, (void*)&b_hh, (void*)&xp, (void*)&hs, (void*)&bar};
    hipLaunchCooperativeKernel((const void*)gru_persistent,
                               dim3(256), blk, args, 0, stream);
  }
  // layer3: (4096x2048)*(1024x2048)^T, relu
  gemm_bt<bf16_t, float><<<dim3(8, 32), blk, 0, stream>>>(hs, W3, b3, out_s, 4096, 1024, 2048, 1);
  // heads (f32 weights, f32 out)
  heads_kernel<<<dim3(4096), blk, 0, stream>>>(out_s, label, W4, b4, W5, b5, W6, b6, Wp, bp, outp);
}

// Round 8
// 2968.053 us; speedup vs baseline: 3.0570x; 1.2807x over previous
//
#include <hip/hip_runtime.h>
#include <hip/hip_bf16.h>
#include <math.h>

// B=32, T=128, D_IN=32, H1=1024, H=2048, PEN=1024, C=64, P=4
// Inputs/outputs FLOAT32 (+int32 labels). Internals bf16 (threshold 1.02e-2).

typedef __bf16 bf16_t;
typedef __bf16 bf16x4 __attribute__((ext_vector_type(4)));
typedef __bf16 bf16x8 __attribute__((ext_vector_type(8)));
typedef float  f32x4  __attribute__((ext_vector_type(4)));

static __device__ __forceinline__ void zero4(f32x4& v) {
  v[0] = 0.0f; v[1] = 0.0f; v[2] = 0.0f; v[3] = 0.0f;
}

template <typename T>
static __device__ __forceinline__ bf16x8 load8_as_bf16(const T* p);
template <>
__device__ __forceinline__ bf16x8 load8_as_bf16<bf16_t>(const bf16_t* p) {
  return *(const bf16x8*)p;
}
template <>
__device__ __forceinline__ bf16x8 load8_as_bf16<float>(const float* p) {
  bf16x8 v;
#pragma unroll
  for (int u = 0; u < 8; ++u) v[u] = (bf16_t)p[u];
  return v;
}

// ---------------------------------------------------------------------------
// GEMM: C[M,N] = act(A[M,K] * Bm[N,K]^T + bias[N]), row-major, bf16 C.
// 128x128 tile, BK=32, 4 waves 2x2, mfma_f32_16x16x32_bf16. (round-4, passing)
// ---------------------------------------------------------------------------
template <typename TA, typename TB>
__global__ __launch_bounds__(256) void gemm_bt(
    const TA* __restrict__ A, const TB* __restrict__ Bm,
    const float* __restrict__ bias, bf16_t* __restrict__ C,
    int M, int N, int K, int relu)
{
  __shared__ __align__(16) bf16_t As[128 * 32];
  __shared__ __align__(16) bf16_t Bs[128 * 32];

  const int tid  = threadIdx.x;
  const int lane = tid & 63;
  const int wave = tid >> 6;
  const int q    = lane >> 4;
  const int l15  = lane & 15;
  const int wr   = wave >> 1;
  const int wc   = wave & 1;
  const int m0   = blockIdx.y * 128;
  const int n0   = blockIdx.x * 128;

  f32x4 acc[4][4];
#pragma unroll
  for (int i = 0; i < 4; ++i)
#pragma unroll
    for (int j = 0; j < 4; ++j) zero4(acc[i][j]);

  const int se = wave * 512 + lane * 8;

  const int kt_count = K >> 5;
  for (int kt = 0; kt < kt_count; ++kt) {
    const int k0 = kt << 5;

    bf16x8 av[2], bv[2];
#pragma unroll
    for (int c = 0; c < 2; ++c) {
      const int e   = c * 2048 + se;
      const int row = e >> 5;
      const int col = e & 31;
      av[c] = load8_as_bf16<TA>(&A [(size_t)(m0 + row) * K + k0 + col]);
      bv[c] = load8_as_bf16<TB>(&Bm[(size_t)(n0 + row) * K + k0 + col]);
    }

    __syncthreads();
#pragma unroll
    for (int c = 0; c < 2; ++c) {
      *(bf16x8*)&As[c * 2048 + se] = av[c];
      *(bf16x8*)&Bs[c * 2048 + se] = bv[c];
    }
    __syncthreads();

    bf16x8 af[4], bfv[4];
#pragma unroll
    for (int i = 0; i < 4; ++i)
      af[i] = *(const bf16x8*)&As[(wr * 64 + i * 16 + l15) * 32 + q * 8];
#pragma unroll
    for (int j = 0; j < 4; ++j)
      bfv[j] = *(const bf16x8*)&Bs[(wc * 64 + j * 16 + l15) * 32 + q * 8];

#pragma unroll
    for (int i = 0; i < 4; ++i)
#pragma unroll
      for (int j = 0; j < 4; ++j)
        acc[i][j] = __builtin_amdgcn_mfma_f32_16x16x32_bf16(af[i], bfv[j], acc[i][j], 0, 0, 0);
  }

#pragma unroll
  for (int j = 0; j < 4; ++j) {
    const int n = n0 + wc * 64 + j * 16 + l15;
    const float bvl = bias[n];
#pragma unroll
    for (int i = 0; i < 4; ++i) {
      const int mbase = m0 + wr * 64 + i * 16 + q * 4;
#pragma unroll
      for (int r = 0; r < 4; ++r) {
        float v = acc[i][j][r] + bvl;
        if (relu) v = v > 0.0f ? v : 0.0f;
        C[(size_t)(mbase + r) * N + n] = (bf16_t)v;
      }
    }
  }
}

// ---------------------------------------------------------------------------
// Persistent GRU v3: per-WG W slice lives in LDS (immune to the per-step
// acquire-fence L2 invalidation that was re-streaming W from LLC each step).
// Rows padded by 8 bf16 (stride 2056) -> 2-way bank aliasing only (free).
// Flag-array grid barrier from R7 (passing). 256 WGs x 256 threads.
// ---------------------------------------------------------------------------
#define WROW_STRIDE 2056

__global__ __launch_bounds__(256) void gru_persistent(
    const float* __restrict__ W_hh, const float* __restrict__ b_hh,
    const bf16_t* __restrict__ xp,  bf16_t* __restrict__ hs,
    unsigned* bar)
{
  __shared__ __align__(16) bf16_t Ws[24 * WROW_STRIDE];   // 98.7 KB
  __shared__ __align__(16) float  hp_s[32][33];           // 4.2 KB

  unsigned* flags = bar + 32;   // 256 slots at +128B

  const int tid  = threadIdx.x;
  const int lane = tid & 63;
  const int wave = tid >> 6;
  const int q    = lane >> 4;
  const int l15  = lane & 15;
  const int mt   = wave >> 1;   // m-tile (gate rows)
  const int nt   = wave & 1;    // n-tile (batch)
  const int j0   = blockIdx.x * 8;

  // ---- preload W slice (f32 -> bf16) into LDS, once ----
  // 24 rows x 2048 cols; row = gate*8 + col-within-8; global row =
  // gate*2048 + j0 + (row&7). 512 f32x4-chunks per row.
  for (int c = tid; c < 24 * 512; c += 256) {
    const int row  = c >> 9;
    const int col4 = (c & 511) << 2;
    const int grow = (row >> 3) * 2048 + j0 + (row & 7);
    const float* src = W_hh + (size_t)grow * 2048 + col4;
    bf16x4 v;
#pragma unroll
    for (int u = 0; u < 4; ++u) v[u] = (bf16_t)src[u];
    *(bf16x4*)&Ws[row * WROW_STRIDE + col4] = v;
  }
  __syncthreads();

  const int m_local = mt * 16 + l15;
  const int mrow    = (m_local < 24) ? m_local : 0;   // clamp; result discarded
  const bf16_t* wrow = &Ws[mrow * WROW_STRIDE];
  const int bcol = nt * 16 + l15;

  // pointwise indices
  const int pb  = tid >> 3;
  const int pjj = tid & 7;
  const int pjg = j0 + pjj;
  const float bh_r = b_hh[pjg];
  const float bh_z = b_hh[2048 + pjg];
  const float bh_n = b_hh[4096 + pjg];

  for (int t = 0; t < 128; ++t) {
    f32x4 acc; zero4(acc);
    if (t > 0) {
      const bf16_t* brow = hs + ((size_t)bcol * 128 + (t - 1)) * 2048;
      f32x4 acc0, acc1; zero4(acc0); zero4(acc1);
      for (int k = 0; k < 2048; k += 64) {
        bf16x8 a0 = *(const bf16x8*)&wrow[k + q * 8];
        bf16x8 b0 = *(const bf16x8*)&brow[k + q * 8];
        bf16x8 a1 = *(const bf16x8*)&wrow[k + 32 + q * 8];
        bf16x8 b1 = *(const bf16x8*)&brow[k + 32 + q * 8];
        acc0 = __builtin_amdgcn_mfma_f32_16x16x32_bf16(a0, b0, acc0, 0, 0, 0);
        acc1 = __builtin_amdgcn_mfma_f32_16x16x32_bf16(a1, b1, acc1, 0, 0, 0);
      }
      acc = acc0 + acc1;
    }

#pragma unroll
    for (int r = 0; r < 4; ++r) {
      const int ml = mt * 16 + q * 4 + r;
      if (ml < 24) hp_s[ml][nt * 16 + l15] = acc[r];
    }
    __syncthreads();

    const size_t xrow = (size_t)(pb * 128 + t) * 6144;
    const float xr = (float)xp[xrow + pjg];
    const float xz = (float)xp[xrow + 2048 + pjg];
    const float xn = (float)xp[xrow + 4096 + pjg];
    const float hr = hp_s[pjj][pb]      + bh_r;
    const float hz = hp_s[8 + pjj][pb]  + bh_z;
    const float hn = hp_s[16 + pjj][pb] + bh_n;
    const float r_ = 1.0f / (1.0f + __expf(-(xr + hr)));
    const float z_ = 1.0f / (1.0f + __expf(-(xz + hz)));
    const float n_ = tanhf(xn + r_ * hn);
    const float hp = (t > 0) ? (float)hs[((size_t)pb * 128 + (t - 1)) * 2048 + pjg] : 0.0f;
    const float hnew = (1.0f - z_) * n_ + z_ * hp;
    hs[((size_t)pb * 128 + t) * 2048 + pjg] = (bf16_t)hnew;

    if (t < 127) {
      const unsigned target = (unsigned)(t + 1);
      __syncthreads();                 // all waves' hs stores drained
      if (tid == 0) {
        __threadfence();               // release: write back this XCD's L2
        __hip_atomic_store(&flags[blockIdx.x], target,
                           __ATOMIC_RELAXED, __HIP_MEMORY_SCOPE_AGENT);
      }
      if (blockIdx.x == 0) {
        while (__hip_atomic_load(&flags[tid],
                  __ATOMIC_RELAXED, __HIP_MEMORY_SCOPE_AGENT) < target)
          __builtin_amdgcn_s_sleep(1);
        __syncthreads();
        if (tid == 0) {
          __hip_atomic_store(&bar[0], target,
                             __ATOMIC_RELAXED, __HIP_MEMORY_SCOPE_AGENT);
          __threadfence();             // acquire side for WG0's next step
        }
        __syncthreads();
      } else {
        if (tid == 0) {
          while (__hip_atomic_load(&bar[0],
                    __ATOMIC_RELAXED, __HIP_MEMORY_SCOPE_AGENT) < target)
            __builtin_amdgcn_s_sleep(2);
          __threadfence();             // acquire: invalidate stale lines
        }
        __syncthreads();
      }
    }
  }
}

// ---------------------------------------------------------------------------
// Heads: per (b,t): 3 scalar + 4 sigmoid heads, 1024-dot each, f32 out.
// ---------------------------------------------------------------------------
__global__ __launch_bounds__(256) void heads_kernel(
    const bf16_t* __restrict__ out_s, const int* __restrict__ labels,
    const float* __restrict__ W4, const float* __restrict__ b4,
    const float* __restrict__ W5, const float* __restrict__ b5,
    const float* __restrict__ W6, const float* __restrict__ b6,
    const float* __restrict__ Wp, const float* __restrict__ bp,
    float* __restrict__ out)
{
  const int bt  = blockIdx.x;
  const int b   = bt >> 7;         // T = 128
  const int lab = labels[b];
  const bf16_t* os  = out_s + (size_t)bt * 1024;
  const float* w4  = W4 + (size_t)lab * 1024;
  const float* w5  = W5 + (size_t)lab * 1024;
  const float* w6  = W6 + (size_t)lab * 1024;
  const float* wp0 = Wp + (size_t)lab * 1024;

  float s[7] = {0, 0, 0, 0, 0, 0, 0};
  for (int d = threadIdx.x; d < 1024; d += 256) {
    const float v = (float)os[d];
    s[0] += v * w4[d];
    s[1] += v * w5[d];
    s[2] += v * w6[d];
    s[3] += v * wp0[d];
    s[4] += v * wp0[65536 + d];
    s[5] += v * wp0[131072 + d];
    s[6] += v * wp0[196608 + d];
  }
#pragma unroll
  for (int i = 0; i < 7; ++i)
    for (int off = 32; off > 0; off >>= 1)
      s[i] += __shfl_down(s[i], off, 64);

  __shared__ float red[4][7];
  const int lane = threadIdx.x & 63, wave = threadIdx.x >> 6;
  if (lane == 0)
    for (int i = 0; i < 7; ++i) red[wave][i] = s[i];
  __syncthreads();
  if (threadIdx.x == 0) {
    float tsum[7];
    for (int i = 0; i < 7; ++i)
      tsum[i] = red[0][i] + red[1][i] + red[2][i] + red[3][i];
    out[bt]        = tsum[0] + b4[lab];
    out[4096 + bt] = tsum[1] + b5[lab];
    out[8192 + bt] = tsum[2] + b6[lab];
#pragma unroll
    for (int p = 0; p < 4; ++p) {
      const float v = tsum[3 + p] + bp[p * 64 + lab];
      out[12288 + p * 4096 + bt] = 1.0f / (1.0f + __expf(-v));
    }
  }
}

// ---------------------------------------------------------------------------
extern "C" void kernel_launch(void* const* d_in, const int* in_sizes, int n_in,
                              void* d_out, int out_size, void* d_ws, size_t ws_size,
                              hipStream_t stream)
{
  const float* x     = (const float*)d_in[0];
  const int*   label = (const int*)d_in[1];
  const float* W1    = (const float*)d_in[2];
  const float* b1    = (const float*)d_in[3];
  const float* W2    = (const float*)d_in[4];
  const float* b2    = (const float*)d_in[5];
  const float* W_ih  = (const float*)d_in[6];
  const float* b_ih  = (const float*)d_in[7];
  const float* W_hh  = (const float*)d_in[8];
  const float* b_hh  = (const float*)d_in[9];
  const float* W3    = (const float*)d_in[10];
  const float* b3    = (const float*)d_in[11];
  const float* W4    = (const float*)d_in[12];
  const float* b4    = (const float*)d_in[13];
  const float* W5    = (const float*)d_in[14];
  const float* b5    = (const float*)d_in[15];
  const float* W6    = (const float*)d_in[16];
  const float* b6    = (const float*)d_in[17];
  const float* Wp    = (const float*)d_in[18];
  const float* bp    = (const float*)d_in[19];

  // Workspace (72 MB + 2 KB), liveness-precise:
  //   out1  [0,8MB)    4096x1024  — dead after layer2
  //   out2  [8,24MB)   4096x2048  — dead after xp GEMM
  //   xp    [24,72MB)  4096x6144  — live through GRU
  //   hs    [0,16MB)   (B,T,2048) — overlays out1+out2 head (dead)
  //   out_s [16,24MB)  4096x1024  — overlays out2 tail (dead)
  //   bar   [72MB,+2KB) barrier state (fresh region, memset before GRU)
  char* ws = (char*)d_ws;
  bf16_t*   out1  = (bf16_t*)(ws);
  bf16_t*   out2  = (bf16_t*)(ws + (8u << 20));
  bf16_t*   xp    = (bf16_t*)(ws + (24u << 20));
  bf16_t*   hs    = (bf16_t*)(ws);
  bf16_t*   out_s = (bf16_t*)(ws + (16u << 20));
  unsigned* bar   = (unsigned*)(ws + (72u << 20));
  float*    outp  = (float*)d_out;

  hipMemsetAsync(d_out, 0, (size_t)out_size * sizeof(float), stream);
  hipMemsetAsync(bar, 0, 2048, stream);

  dim3 blk(256);
  // layer1: (4096x32)*(1024x32)^T, relu
  gemm_bt<float, float><<<dim3(8, 32), blk, 0, stream>>>(x, W1, b1, out1, 4096, 1024, 32, 1);
  // layer2: (4096x1024)*(2048x1024)^T, relu
  gemm_bt<bf16_t, float><<<dim3(16, 32), blk, 0, stream>>>(out1, W2, b2, out2, 4096, 2048, 1024, 1);
  // xp: (4096x2048)*(6144x2048)^T + b_ih
  gemm_bt<bf16_t, float><<<dim3(48, 32), blk, 0, stream>>>(out2, W_ih, b_ih, xp, 4096, 6144, 2048, 0);
  // GRU: persistent dispatch, W in LDS, flag-array grid barrier
  {
    void* args[] = {(void*)&W_hh, (void*)&b_hh, (void*)&xp, (void*)&hs, (void*)&bar};
    hipLaunchCooperativeKernel((const void*)gru_persistent,
                               dim3(256), blk, args, 0, stream);
  }
  // layer3: (4096x2048)*(1024x2048)^T, relu
  gemm_bt<bf16_t, float><<<dim3(8, 32), blk, 0, stream>>>(hs, W3, b3, out_s, 4096, 1024, 2048, 1);
  // heads (f32 weights, f32 out)
  heads_kernel<<<dim3(4096), blk, 0, stream>>>(out_s, label, W4, b4, W5, b5, W6, b6, Wp, bp, outp);
}